// Round 6
// baseline (236.312 us; speedup 1.0000x reference)
//
#include <hip/hip_runtime.h>

// sign(tanh(conv1x1(x,W))) == sign(x @ W)
// x: [M=131072, K=512] f32, W: [K=512, N=32] f32, out: [M,N] f32 in {-1,0,1}
//
// R6: R4's double-buffered T14 async-STAGE structure WITHOUT the
// __launch_bounds__ min-wave arg. R2/R4's GB-scale WRITE_SIZE was register
// spill caused by the (256,4) 64-VGPR cap, not by the prefetch itself
// (R4 VGPR_Count == 64 == cap). At ~90 VGPR we still get 4 waves/SIMD.
// Issue next chunk's global loads BEFORE compute (in flight under ~2000cy of
// FMA issue), commit to LDS after compute, one barrier per chunk.
// Padded XSTR=36 -> 0 bank conflicts (measured R4/R5). W read from global
// (L1-hot; staging W in LDS would make the LDS pipe the binding resource).
// |acc| < TAU recomputed in f64 wave-cooperatively -> exact sign.

constexpr int K     = 512;
constexpr int N     = 32;
constexpr int BROWS = 128;          // rows/block -> grid 1024 = 4 blocks/CU
constexpr int KC    = 32;           // k-chunk
constexpr int XSTR  = KC + 4;       // padded LDS row stride (36 floats)
constexpr float TAU = 1e-3f;        // worst-case f32 dot error ~3e-4

__global__ __launch_bounds__(256)   // NO min-wave arg: don't cap VGPRs
void conv_sign_kernel(const float* __restrict__ x,
                      const float* __restrict__ Wm,
                      float* __restrict__ out)
{
    __shared__ float xs[2][BROWS * XSTR];   // 2 x 18 KiB

    const int t = threadIdx.x;
    const int l = t & 63;
    const int w = t >> 6;
    const int block_row = blockIdx.x * BROWS;

    const int r0 = (t >> 3) << 2;   // 4 consecutive rows per thread
    const int c0 = (t & 7) << 2;    // 4 consecutive cols per thread

    const int srow = t >> 3;        // staging row (+ p*32)
    const int sk   = (t & 7) << 2;  // staging float offset within row chunk

    float acc[4][4];
#pragma unroll
    for (int i = 0; i < 4; ++i)
#pragma unroll
        for (int j = 0; j < 4; ++j) acc[i][j] = 0.f;

    float4 stg[4];
    auto issue = [&](int kc) {
#pragma unroll
        for (int p = 0; p < 4; ++p)
            stg[p] = *reinterpret_cast<const float4*>(
                x + (size_t)(block_row + p * 32 + srow) * K + kc + sk);
    };
    auto commit = [&](int buf) {
#pragma unroll
        for (int p = 0; p < 4; ++p)
            *reinterpret_cast<float4*>(&xs[buf][(p * 32 + srow) * XSTR + sk]) = stg[p];
    };

    issue(0);
    commit(0);
    __syncthreads();

    const int NCHUNK = K / KC;      // 16
    for (int tc = 0; tc < NCHUNK; ++tc) {
        const int cur = tc & 1;
        if (tc + 1 < NCHUNK) issue((tc + 1) * KC);   // loads fly under compute

        const float* xb = &xs[cur][r0 * XSTR];
        const float* wb = Wm + tc * KC * N + c0;     // W from global (L1-hot)
#pragma unroll
        for (int k4 = 0; k4 < KC / 4; ++k4) {
            float4 xv[4], wv[4];
#pragma unroll
            for (int i = 0; i < 4; ++i)
                xv[i] = *reinterpret_cast<const float4*>(xb + i * XSTR + k4 * 4);
#pragma unroll
            for (int j = 0; j < 4; ++j)
                wv[j] = *reinterpret_cast<const float4*>(wb + (k4 * 4 + j) * N);
#pragma unroll
            for (int i = 0; i < 4; ++i) {
#pragma unroll
                for (int j = 0; j < 4; ++j) {
                    const float xk = (&xv[i].x)[j];
                    acc[i][0] += xk * wv[j].x;
                    acc[i][1] += xk * wv[j].y;
                    acc[i][2] += xk * wv[j].z;
                    acc[i][3] += xk * wv[j].w;
                }
            }
        }

        if (tc + 1 < NCHUNK) {
            commit(cur ^ 1);        // vmcnt wait lands here, ~free
            __syncthreads();        // one barrier per chunk
        }
    }

    // ---- exact f64 fixup for ambiguous accumulators (rare) ----
#pragma unroll
    for (int ai = 0; ai < 4; ++ai) {
#pragma unroll
        for (int bi = 0; bi < 4; ++bi) {
            unsigned long long bal = __ballot(fabsf(acc[ai][bi]) < TAU);
            while (bal) {
                const int s = __ffsll(bal) - 1;
                bal &= bal - 1;
                const int gr = block_row + 32 * w + ((s >> 3) << 2) + ai;
                const int gc = ((s & 7) << 2) + bi;
                const float* xr = x  + (size_t)gr * K + l * 8;
                const float* wr = Wm + (size_t)(l * 8) * N + gc;
                double part = 0.0;
#pragma unroll
                for (int q = 0; q < 8; ++q)
                    part += (double)xr[q] * (double)wr[q * N];
#pragma unroll
                for (int off = 32; off > 0; off >>= 1)
                    part += __shfl_xor(part, off);
                if (l == s)
                    acc[ai][bi] = (part > 0.0) ? 2.f : ((part < 0.0) ? -2.f : 0.f);
            }
        }
    }

    // ---- sign + store: 8 col-lane groups cover a 128B output row ----
#pragma unroll
    for (int i = 0; i < 4; ++i) {
        const int gr = block_row + r0 + i;
        float4 o;
        o.x = (acc[i][0] > 0.f) ? 1.f : ((acc[i][0] < 0.f) ? -1.f : 0.f);
        o.y = (acc[i][1] > 0.f) ? 1.f : ((acc[i][1] < 0.f) ? -1.f : 0.f);
        o.z = (acc[i][2] > 0.f) ? 1.f : ((acc[i][2] < 0.f) ? -1.f : 0.f);
        o.w = (acc[i][3] > 0.f) ? 1.f : ((acc[i][3] < 0.f) ? -1.f : 0.f);
        *reinterpret_cast<float4*>(out + (size_t)gr * N + c0) = o;
    }
}

extern "C" void kernel_launch(void* const* d_in, const int* in_sizes, int n_in,
                              void* d_out, int out_size, void* d_ws, size_t ws_size,
                              hipStream_t stream)
{
    const float* x  = (const float*)d_in[0];
    const float* Wm = (const float*)d_in[1];
    float* out      = (float*)d_out;
    const int M     = in_sizes[0] / K;            // 131072
    const int grid  = M / BROWS;                  // 1024
    hipLaunchKernelGGL(conv_sign_kernel, dim3(grid), dim3(256), 0, stream,
                       x, Wm, out);
}

// Round 7
// 105.267 us; speedup vs baseline: 2.2449x; 2.2449x over previous
//
#include <hip/hip_runtime.h>

// sign(tanh(conv1x1(x,W))) == sign(x @ W)
// x: [M=131072, K=512] f32, W: [K=512, N=32] f32, out: [M,N] f32 in {-1,0,1}
//
// R7: wave-uniform column tiling + scalar-pipe W + in-block K-split.
//  - wave w: cols 8*(w&3) .. +7 (uniform per wave -> W loads become s_load,
//    off the LDS and VALU-load pipes entirely), K-half (w>>2)*256.
//  - lane l: rows 4l..4l+3. x ds_read_b128 = 64 distinct rows = 1KB/instr
//    (R1 wasted 4x on shared addresses): LDS pipe 61 -> 20 us/CU.
//  - 512 threads, grid 512 -> 16 waves/CU; single-buffered staging (R5's
//    proven low-VGPR shape; R4/R6 showed reg-prefetch spills or balloons).
//  - K-halves merged through LDS; |sum| < TAU recomputed in f64 by the
//    whole wave -> exact sign.

constexpr int K     = 512;
constexpr int N     = 32;
constexpr int BROWS = 256;
constexpr int KC    = 32;
constexpr int XSTR  = 36;           // padded row stride (floats)
constexpr float TAU = 1e-3f;        // worst-case f32 error ~3e-4 (any order)

__global__ __launch_bounds__(512)
void conv_sign_kernel(const float* __restrict__ x,
                      const float* __restrict__ Wm,
                      float* __restrict__ out)
{
    __shared__ float xs[2][BROWS * XSTR];   // 73.7 KiB: both K-halves' chunks

    const int t  = threadIdx.x;
    const int l  = t & 63;
    const int wv = t >> 6;                  // 0..7
    const int c0    = __builtin_amdgcn_readfirstlane((wv & 3) << 3);  // uniform cols
    const int kbase = __builtin_amdgcn_readfirstlane((wv >> 2) << 8); // uniform K-half
    const int kh    = wv >> 2;
    const int block_row = blockIdx.x * BROWS;
    const int r0 = l << 2;                  // rows 4l..4l+3

    float acc[4][8];
#pragma unroll
    for (int i = 0; i < 4; ++i)
#pragma unroll
        for (int j = 0; j < 8; ++j) acc[i][j] = 0.f;

    for (int tc = 0; tc < (K / 2) / KC; ++tc) {   // 8 chunks per half
        const int kc = tc * KC;                   // offset within half
        if (tc) __syncthreads();
        // ---- stage BOTH halves' chunks: 4096 16B-units, 8 per thread ----
#pragma unroll
        for (int p = 0; p < 8; ++p) {
            const int u  = t + (p << 9);
            const int h  = u >> 11;               // which K-half
            const int v  = u & 2047;
            const int r  = v >> 3;                // row 0..255
            const int sl = (v & 7) << 2;          // float offset in chunk
            const float4 d = *reinterpret_cast<const float4*>(
                x + (size_t)(block_row + r) * K + (h << 8) + kc + sl);
            *reinterpret_cast<float4*>(&xs[h][r * XSTR + sl]) = d;
        }
        __syncthreads();

        const float* xb = &xs[kh][0];
#pragma unroll
        for (int k4 = 0; k4 < KC / 4; ++k4) {
            float4 xv[4];
#pragma unroll
            for (int i = 0; i < 4; ++i)
                xv[i] = *reinterpret_cast<const float4*>(
                    xb + (r0 + i) * XSTR + (k4 << 2));
#pragma unroll
            for (int kk = 0; kk < 4; ++kk) {
                // wave-uniform address -> scalar loads (SMEM pipe)
                const float* wr = Wm + (size_t)(kbase + kc + (k4 << 2) + kk) * N + c0;
#pragma unroll
                for (int j = 0; j < 8; ++j) {
                    const float wj = wr[j];
#pragma unroll
                    for (int i = 0; i < 4; ++i)
                        acc[i][j] += (&xv[i].x)[kk] * wj;
                }
            }
        }
    }

    // ---- merge K-halves through LDS (stride 36 to spread banks) ----
    __syncthreads();
    if (kh == 1) {
        float* dst = &xs[0][0] + (((wv & 3) << 6) + l) * 36;
#pragma unroll
        for (int i = 0; i < 4; ++i)
#pragma unroll
            for (int j = 0; j < 8; ++j) dst[i * 8 + j] = acc[i][j];
    }
    __syncthreads();
    if (kh == 1) return;                    // upper waves done (no more barriers)
    {
        const float* src = &xs[0][0] + (((wv & 3) << 6) + l) * 36;
#pragma unroll
        for (int i = 0; i < 4; ++i)
#pragma unroll
            for (int j = 0; j < 8; ++j) acc[i][j] += src[i * 8 + j];
    }

    // ---- exact f64 fixup for ambiguous sums (rare) ----
#pragma unroll
    for (int ai = 0; ai < 4; ++ai) {
#pragma unroll
        for (int bi = 0; bi < 8; ++bi) {
            unsigned long long bal = __ballot(fabsf(acc[ai][bi]) < TAU);
            while (bal) {
                const int s = __ffsll(bal) - 1;
                bal &= bal - 1;
                const int gr = block_row + (s << 2) + ai;
                const int gc = c0 + bi;
                const float* xr = x  + (size_t)gr * K + l * 8;
                const float* wr = Wm + (size_t)(l * 8) * N + gc;
                double part = 0.0;
#pragma unroll
                for (int q = 0; q < 8; ++q)
                    part += (double)xr[q] * (double)wr[q * N];
#pragma unroll
                for (int off = 32; off > 0; off >>= 1)
                    part += __shfl_xor(part, off);
                if (l == s)
                    acc[ai][bi] = (part > 0.0) ? 2.f : ((part < 0.0) ? -2.f : 0.f);
            }
        }
    }

    // ---- sign + store: 2 float4 per owned row ----
#pragma unroll
    for (int i = 0; i < 4; ++i) {
        const int gr = block_row + r0 + i;
        float4 o0, o1;
        o0.x = (acc[i][0] > 0.f) ? 1.f : ((acc[i][0] < 0.f) ? -1.f : 0.f);
        o0.y = (acc[i][1] > 0.f) ? 1.f : ((acc[i][1] < 0.f) ? -1.f : 0.f);
        o0.z = (acc[i][2] > 0.f) ? 1.f : ((acc[i][2] < 0.f) ? -1.f : 0.f);
        o0.w = (acc[i][3] > 0.f) ? 1.f : ((acc[i][3] < 0.f) ? -1.f : 0.f);
        o1.x = (acc[i][4] > 0.f) ? 1.f : ((acc[i][4] < 0.f) ? -1.f : 0.f);
        o1.y = (acc[i][5] > 0.f) ? 1.f : ((acc[i][5] < 0.f) ? -1.f : 0.f);
        o1.z = (acc[i][6] > 0.f) ? 1.f : ((acc[i][6] < 0.f) ? -1.f : 0.f);
        o1.w = (acc[i][7] > 0.f) ? 1.f : ((acc[i][7] < 0.f) ? -1.f : 0.f);
        float4* dst = reinterpret_cast<float4*>(out + (size_t)gr * N + c0);
        dst[0] = o0;
        dst[1] = o1;
    }
}

extern "C" void kernel_launch(void* const* d_in, const int* in_sizes, int n_in,
                              void* d_out, int out_size, void* d_ws, size_t ws_size,
                              hipStream_t stream)
{
    const float* x  = (const float*)d_in[0];
    const float* Wm = (const float*)d_in[1];
    float* out      = (float*)d_out;
    const int M     = in_sizes[0] / K;            // 131072
    const int grid  = M / BROWS;                  // 512
    hipLaunchKernelGGL(conv_sign_kernel, dim3(grid), dim3(512), 0, stream,
                       x, Wm, out);
}

// Round 8
// 102.867 us; speedup vs baseline: 2.2973x; 1.0233x over previous
//
#include <hip/hip_runtime.h>

// sign(tanh(conv1x1(x,W))) == sign(x @ W)
// x: [M=131072, K=512] f32, W: [K=512, N=32] f32, out: [M,N] f32 in {-1,0,1}
//
// R8 = R7 + XOR slot swizzle on the x tile (T2 adapted to reg-staged LDS).
// R7 measured 1.26e7 bank-conflict cycles: lane l reads rows 4l..4l+3 at
// 576B lane stride -> bank step 16 -> ~4-way conflicts on ds_read_b128.
// Swizzle phys_slot = slot ^ ((row>>2)&7) on BOTH stage-write and read:
// read bank-quad = (4l + i + (k4 ^ (l&7))) mod 8 -> distinct per 8-lane
// phase; l and l+8 alias 2-way (free, m136). Writes remain a within-row
// permutation (conflict-free).
// Everything else is R7 (verified): wave-uniform cols -> W on scalar pipe,
// 1KB/instr x-reads, in-block K-split, single-buffered staging, low VGPR.
// |sum| < TAU recomputed in f64 wave-cooperatively -> exact sign.

constexpr int K     = 512;
constexpr int N     = 32;
constexpr int BROWS = 256;
constexpr int KC    = 32;
constexpr int XSTR  = 36;           // padded row stride (floats), 16B-aligned rows
constexpr float TAU = 1e-3f;        // worst-case f32 error ~3e-4 (any order)

__global__ __launch_bounds__(512)
void conv_sign_kernel(const float* __restrict__ x,
                      const float* __restrict__ Wm,
                      float* __restrict__ out)
{
    __shared__ float xs[2][BROWS * XSTR];   // 73.7 KiB: both K-halves' chunks

    const int t  = threadIdx.x;
    const int l  = t & 63;
    const int wv = t >> 6;                  // 0..7
    const int c0    = __builtin_amdgcn_readfirstlane((wv & 3) << 3);  // uniform cols
    const int kbase = __builtin_amdgcn_readfirstlane((wv >> 2) << 8); // uniform K-half
    const int kh    = wv >> 2;
    const int block_row = blockIdx.x * BROWS;
    const int r0 = l << 2;                  // rows 4l..4l+3

    float acc[4][8];
#pragma unroll
    for (int i = 0; i < 4; ++i)
#pragma unroll
        for (int j = 0; j < 8; ++j) acc[i][j] = 0.f;

    for (int tc = 0; tc < (K / 2) / KC; ++tc) {   // 8 chunks per half
        const int kc = tc * KC;                   // offset within half
        if (tc) __syncthreads();
        // ---- stage BOTH halves' chunks: 4096 16B-units, 8 per thread ----
#pragma unroll
        for (int p = 0; p < 8; ++p) {
            const int u  = t + (p << 9);
            const int h  = u >> 11;               // which K-half
            const int v  = u & 2047;
            const int r  = v >> 3;                // row 0..255
            const int s  = v & 7;                 // logical 16B slot
            const int ps = s ^ ((r >> 2) & 7);    // swizzled physical slot
            const float4 d = *reinterpret_cast<const float4*>(
                x + (size_t)(block_row + r) * K + (h << 8) + kc + (s << 2));
            *reinterpret_cast<float4*>(&xs[h][r * XSTR + (ps << 2)]) = d;
        }
        __syncthreads();

        const float* xb = &xs[kh][0];
        const int lswz = l & 7;
#pragma unroll
        for (int k4 = 0; k4 < KC / 4; ++k4) {
            const int ps = (k4 ^ lswz) << 2;      // swizzled read slot
            float4 xv[4];
#pragma unroll
            for (int i = 0; i < 4; ++i)
                xv[i] = *reinterpret_cast<const float4*>(
                    xb + (r0 + i) * XSTR + ps);
#pragma unroll
            for (int kk = 0; kk < 4; ++kk) {
                // wave-uniform address -> scalar loads (SMEM pipe)
                const float* wr = Wm + (size_t)(kbase + kc + (k4 << 2) + kk) * N + c0;
#pragma unroll
                for (int j = 0; j < 8; ++j) {
                    const float wj = wr[j];
#pragma unroll
                    for (int i = 0; i < 4; ++i)
                        acc[i][j] += (&xv[i].x)[kk] * wj;
                }
            }
        }
    }

    // ---- merge K-halves through LDS (stride 36 to spread banks) ----
    __syncthreads();
    if (kh == 1) {
        float* dst = &xs[0][0] + (((wv & 3) << 6) + l) * 36;
#pragma unroll
        for (int i = 0; i < 4; ++i)
#pragma unroll
            for (int j = 0; j < 8; ++j) dst[i * 8 + j] = acc[i][j];
    }
    __syncthreads();
    if (kh == 1) return;                    // upper waves done (no more barriers)
    {
        const float* src = &xs[0][0] + (((wv & 3) << 6) + l) * 36;
#pragma unroll
        for (int i = 0; i < 4; ++i)
#pragma unroll
            for (int j = 0; j < 8; ++j) acc[i][j] += src[i * 8 + j];
    }

    // ---- exact f64 fixup for ambiguous sums (rare) ----
#pragma unroll
    for (int ai = 0; ai < 4; ++ai) {
#pragma unroll
        for (int bi = 0; bi < 8; ++bi) {
            unsigned long long bal = __ballot(fabsf(acc[ai][bi]) < TAU);
            while (bal) {
                const int s = __ffsll(bal) - 1;
                bal &= bal - 1;
                const int gr = block_row + (s << 2) + ai;
                const int gc = c0 + bi;
                const float* xr = x  + (size_t)gr * K + l * 8;
                const float* wr = Wm + (size_t)(l * 8) * N + gc;
                double part = 0.0;
#pragma unroll
                for (int q = 0; q < 8; ++q)
                    part += (double)xr[q] * (double)wr[q * N];
#pragma unroll
                for (int off = 32; off > 0; off >>= 1)
                    part += __shfl_xor(part, off);
                if (l == s)
                    acc[ai][bi] = (part > 0.0) ? 2.f : ((part < 0.0) ? -2.f : 0.f);
            }
        }
    }

    // ---- sign + store: 2 float4 per owned row ----
#pragma unroll
    for (int i = 0; i < 4; ++i) {
        const int gr = block_row + r0 + i;
        float4 o0, o1;
        o0.x = (acc[i][0] > 0.f) ? 1.f : ((acc[i][0] < 0.f) ? -1.f : 0.f);
        o0.y = (acc[i][1] > 0.f) ? 1.f : ((acc[i][1] < 0.f) ? -1.f : 0.f);
        o0.z = (acc[i][2] > 0.f) ? 1.f : ((acc[i][2] < 0.f) ? -1.f : 0.f);
        o0.w = (acc[i][3] > 0.f) ? 1.f : ((acc[i][3] < 0.f) ? -1.f : 0.f);
        o1.x = (acc[i][4] > 0.f) ? 1.f : ((acc[i][4] < 0.f) ? -1.f : 0.f);
        o1.y = (acc[i][5] > 0.f) ? 1.f : ((acc[i][5] < 0.f) ? -1.f : 0.f);
        o1.z = (acc[i][6] > 0.f) ? 1.f : ((acc[i][6] < 0.f) ? -1.f : 0.f);
        o1.w = (acc[i][7] > 0.f) ? 1.f : ((acc[i][7] < 0.f) ? -1.f : 0.f);
        float4* dst = reinterpret_cast<float4*>(out + (size_t)gr * N + c0);
        dst[0] = o0;
        dst[1] = o1;
    }
}

extern "C" void kernel_launch(void* const* d_in, const int* in_sizes, int n_in,
                              void* d_out, int out_size, void* d_ws, size_t ws_size,
                              hipStream_t stream)
{
    const float* x  = (const float*)d_in[0];
    const float* Wm = (const float*)d_in[1];
    float* out      = (float*)d_out;
    const int M     = in_sizes[0] / K;            // 131072
    const int grid  = M / BROWS;                  // 512
    hipLaunchKernelGGL(conv_sign_kernel, dim3(grid), dim3(512), 0, stream,
                       x, Wm, out);
}

// Round 9
// 97.921 us; speedup vs baseline: 2.4133x; 1.0505x over previous
//
#include <hip/hip_runtime.h>

// sign(tanh(conv1x1(x,W))) == sign(x @ W)
// x: [M=131072, K=512] f32, W: [K=512, N=32] f32, out: [M,N] f32 in {-1,0,1}
//
// R9: lane-owns-a-row streaming GEMV. Each lane computes one full output row
// (32 cols, full K) -> x needs NO cross-lane sharing: no LDS, no barriers,
// no staging. W addresses are lane-uniform (scalar/broadcast, L1-hot 64 KB).
// Latency hidden by 2-deep k-window prefetch (8 dwordx4 in flight per lane);
// x walks 64B lines sequentially (R3 measured this pattern near-clean).
// |acc| < TAU recomputed in f64 wave-cooperatively -> exact sign.
//
// Journal: R1/R5/R7/R8 barrier-synced LDS loops all idle both pipes
// (VALU ~20%, HBM ~12%) regardless of conflicts/swizzle; R8 proved
// conflicts were only ~3us. The structure was the bottleneck.

constexpr int K   = 512;
constexpr int N   = 32;
constexpr float TAU = 1e-3f;        // worst-case f32 dot error ~3e-4

__global__ __launch_bounds__(256)
void conv_sign_kernel(const float* __restrict__ x,
                      const float* __restrict__ Wm,
                      float* __restrict__ out)
{
    const int t  = threadIdx.x;
    const int l  = t & 63;
    const int wv = t >> 6;
    const int block_row = blockIdx.x * 256;
    const int row = block_row + wv * 64 + l;        // lane-owned row
    const float* xr = x + (size_t)row * K;

    float acc[N];
#pragma unroll
    for (int c = 0; c < N; ++c) acc[c] = 0.f;

    float4 cur[8], nxt[8];
#pragma unroll
    for (int j = 0; j < 8; ++j)
        cur[j] = *reinterpret_cast<const float4*>(xr + j * 4);

#pragma unroll 1
    for (int kw = 0; kw < 16; ++kw) {               // 16 windows of 32 k
        const int kn = (kw + 1) & 15;               // wrap: dead reload at tail
#pragma unroll
        for (int j = 0; j < 8; ++j)                 // prefetch next window
            nxt[j] = *reinterpret_cast<const float4*>(xr + kn * 32 + j * 4);

#pragma unroll
        for (int j = 0; j < 8; ++j) {               // consume current window
#pragma unroll
            for (int kk = 0; kk < 4; ++kk) {
                const float xv = (&cur[j].x)[kk];
                const float* wr = Wm + (size_t)(kw * 32 + j * 4 + kk) * N;
#pragma unroll
                for (int c4 = 0; c4 < 8; ++c4) {    // uniform addr -> s_load
                    const float4 wq = *reinterpret_cast<const float4*>(wr + c4 * 4);
                    acc[c4 * 4 + 0] += xv * wq.x;
                    acc[c4 * 4 + 1] += xv * wq.y;
                    acc[c4 * 4 + 2] += xv * wq.z;
                    acc[c4 * 4 + 3] += xv * wq.w;
                }
            }
        }
#pragma unroll
        for (int j = 0; j < 8; ++j) cur[j] = nxt[j];  // static-index ping-pong
    }

    // ---- exact f64 fixup for ambiguous sums (rare, ~1e-3 rate) ----
#pragma unroll 1
    for (int c = 0; c < N; ++c) {
        unsigned long long bal = __ballot(fabsf(acc[c]) < TAU);
        while (bal) {
            const int s = __ffsll(bal) - 1;
            bal &= bal - 1;
            const int gr = block_row + wv * 64 + s;   // lane s's row
            const float* xf = x  + (size_t)gr * K + l * 8;
            const float* wf = Wm + (size_t)(l * 8) * N + c;
            double part = 0.0;
#pragma unroll
            for (int q = 0; q < 8; ++q)
                part += (double)xf[q] * (double)wf[q * N];
#pragma unroll
            for (int off = 32; off > 0; off >>= 1)
                part += __shfl_xor(part, off);
            if (l == s)
                acc[c] = (part > 0.0) ? 2.f : ((part < 0.0) ? -2.f : 0.f);
        }
    }

    // ---- sign + store: lane writes its whole 128B row (lines filled by
    //      consecutive stores; lanes' rows contiguous across the wave) ----
    float* orow = out + (size_t)row * N;
#pragma unroll
    for (int c4 = 0; c4 < 8; ++c4) {
        float4 o;
        o.x = (acc[c4*4+0] > 0.f) ? 1.f : ((acc[c4*4+0] < 0.f) ? -1.f : 0.f);
        o.y = (acc[c4*4+1] > 0.f) ? 1.f : ((acc[c4*4+1] < 0.f) ? -1.f : 0.f);
        o.z = (acc[c4*4+2] > 0.f) ? 1.f : ((acc[c4*4+2] < 0.f) ? -1.f : 0.f);
        o.w = (acc[c4*4+3] > 0.f) ? 1.f : ((acc[c4*4+3] < 0.f) ? -1.f : 0.f);
        *reinterpret_cast<float4*>(orow + c4 * 4) = o;
    }
}

extern "C" void kernel_launch(void* const* d_in, const int* in_sizes, int n_in,
                              void* d_out, int out_size, void* d_ws, size_t ws_size,
                              hipStream_t stream)
{
    const float* x  = (const float*)d_in[0];
    const float* Wm = (const float*)d_in[1];
    float* out      = (float*)d_out;
    const int M     = in_sizes[0] / K;            // 131072
    const int grid  = M / 256;                    // 512
    hipLaunchKernelGGL(conv_sign_kernel, dim3(grid), dim3(256), 0, stream,
                       x, Wm, out);
}